// Round 1
// baseline (441.671 us; speedup 1.0000x reference)
//
#include <hip/hip_runtime.h>
#include <cstdint>
#include <cstddef>

#define IN_F 4096
#define OUT_F 4096
#define RANKK 16
#define EPSQ 1e-8f
#define LSCALE 0.01f

typedef __attribute__((ext_vector_type(4))) int i32x4;
typedef __attribute__((ext_vector_type(16))) int i32x16;

__device__ __forceinline__ float quantf(float v, float s) {
    float q = rintf(v / s);             // RNE, matches jnp.round
    return fminf(7.f, fmaxf(-8.f, q));
}

// ---------------------------------------------------------------------------
// Kernel 1: quantize activations x -> int8 in [-8,7].  4 elems/thread.
// ---------------------------------------------------------------------------
__global__ __launch_bounds__(256) void qx_kernel(const float* __restrict__ x,
                                                 const float* __restrict__ ascale,
                                                 int8_t* __restrict__ qx) {
    const float asc = fmaxf(fabsf(ascale[0]), EPSQ);
    const int i = blockIdx.x * 256 + threadIdx.x;
    float4 v = ((const float4*)x)[i];
    union { int8_t b[4]; int w; } u;
    u.b[0] = (int8_t)(int)quantf(v.x, asc);
    u.b[1] = (int8_t)(int)quantf(v.y, asc);
    u.b[2] = (int8_t)(int)quantf(v.z, asc);
    u.b[3] = (int8_t)(int)quantf(v.w, asc);
    ((int*)qx)[i] = u.w;
}

// ---------------------------------------------------------------------------
// Kernel 2: merged = W + 0.01 * (lora_B @ lora_A); quantize per output row.
// Block tile: 64 rows (o) x 256 cols (i); LDS-staged A-tile and B-tile so the
// rank-16 operands are read O(1) times from global.
// ---------------------------------------------------------------------------
__global__ __launch_bounds__(256) void qw_kernel(const float* __restrict__ W,
                                                 const float* __restrict__ lA,
                                                 const float* __restrict__ lB,
                                                 const float* __restrict__ wscale,
                                                 int8_t* __restrict__ qw) {
    __shared__ float Ablk[RANKK][256];   // 16 KB
    __shared__ float Bblk[64][RANKK];    // 4 KB
    const int tid = threadIdx.x;
    const int i0 = blockIdx.x * 256;
    const int o0 = blockIdx.y * 64;

#pragma unroll
    for (int r = 0; r < RANKK; ++r)
        Ablk[r][tid] = lA[r * IN_F + i0 + tid];
    for (int j = tid; j < 64 * RANKK; j += 256)
        Bblk[j >> 4][j & 15] = lB[(size_t)(o0 + (j >> 4)) * RANKK + (j & 15)];
    __syncthreads();

    const int i = i0 + tid;
    for (int o = 0; o < 64; ++o) {
        float s = 0.f;
#pragma unroll
        for (int r = 0; r < RANKK; ++r) s += Bblk[o][r] * Ablk[r][tid];
        float merged = W[(size_t)(o0 + o) * IN_F + i] + LSCALE * s;
        float wsc = fmaxf(fabsf(wscale[o0 + o]), EPSQ);
        qw[(size_t)(o0 + o) * IN_F + i] = (int8_t)(int)quantf(merged, wsc);
    }
}

// ---------------------------------------------------------------------------
// Kernel 3: int8 GEMM  out[m,n] = asc*wsc[n]*(q_x[m,:]·q_w[n,:]) + bias[n]
// 128x128 tile, BK=64, 4 waves each computing 64x64 via 2x2 mfma_i32_32x32x32_i8.
// global_load_lds(16B) staging with XOR chunk swizzle:
//   16B-chunk of (row m, k-chunk q) stored at LDS slot (m, q ^ ((m>>1)&3))
// so every 8-lane phase group of ds_read_b128 hits all 32 banks exactly once.
// ---------------------------------------------------------------------------
constexpr int BM = 128, BN = 128, BK = 64, KD = 4096;

__global__ __launch_bounds__(256) void gemm_i8_kernel(
        const int8_t* __restrict__ qx, const int8_t* __restrict__ qw,
        const float* __restrict__ wscale, const float* __restrict__ ascale,
        const float* __restrict__ bias, float* __restrict__ out) {
    __shared__ __attribute__((aligned(16))) int8_t As[BM * BK];  // 8 KB
    __shared__ __attribute__((aligned(16))) int8_t Bs[BN * BK];  // 8 KB

    const int tid  = threadIdx.x;
    const int lane = tid & 63;
    const int wave = tid >> 6;
    const int m_tile = blockIdx.y * BM;
    const int n_tile = blockIdx.x * BN;
    const int wm = (wave >> 1) * 64;   // wave row offset in tile
    const int wn = (wave & 1) * 64;    // wave col offset in tile

    // Staging: LDS chunk index p = wave*128 + issue*64 + lane holds global
    // chunk (m = p>>2, q = (p&3) ^ ((m>>1)&3)).
    int stage_off[2];
#pragma unroll
    for (int is = 0; is < 2; ++is) {
        int p = wave * 128 + is * 64 + lane;
        int m = p >> 2;
        int q = (p & 3) ^ ((m >> 1) & 3);
        stage_off[is] = m * KD + q * 16;
    }
    const int8_t* Abase = qx + (size_t)m_tile * KD;
    const int8_t* Bbase = qw + (size_t)n_tile * KD;

    // Fragment LDS byte addresses. A-frag for 32x32x32: row = lane&31,
    // k = kk*32 + (lane>>5)*16 + j  -> needed chunk q = kk*2 + (lane>>5).
    int rdA[2][2], rdB[2][2];
#pragma unroll
    for (int mi = 0; mi < 2; ++mi) {
        const int ra = wm + mi * 32 + (lane & 31);
        const int rb = wn + mi * 32 + (lane & 31);
#pragma unroll
        for (int kk = 0; kk < 2; ++kk) {
            const int qn = kk * 2 + (lane >> 5);
            rdA[mi][kk] = ra * 64 + ((qn ^ ((ra >> 1) & 3)) * 16);
            rdB[mi][kk] = rb * 64 + ((qn ^ ((rb >> 1) & 3)) * 16);
        }
    }

    i32x16 acc[2][2];
#pragma unroll
    for (int mi = 0; mi < 2; ++mi)
#pragma unroll
        for (int ni = 0; ni < 2; ++ni) acc[mi][ni] = (i32x16)(0);

    for (int k0 = 0; k0 < KD; k0 += BK) {
#pragma unroll
        for (int is = 0; is < 2; ++is) {
            __builtin_amdgcn_global_load_lds(
                (const __attribute__((address_space(1))) void*)(Abase + k0 + stage_off[is]),
                (__attribute__((address_space(3))) void*)(As + wave * 2048 + is * 1024),
                16, 0, 0);
            __builtin_amdgcn_global_load_lds(
                (const __attribute__((address_space(1))) void*)(Bbase + k0 + stage_off[is]),
                (__attribute__((address_space(3))) void*)(Bs + wave * 2048 + is * 1024),
                16, 0, 0);
        }
        __syncthreads();
#pragma unroll
        for (int kk = 0; kk < 2; ++kk) {
            i32x4 af[2], bf[2];
#pragma unroll
            for (int mi = 0; mi < 2; ++mi) af[mi] = *(const i32x4*)(As + rdA[mi][kk]);
#pragma unroll
            for (int ni = 0; ni < 2; ++ni) bf[ni] = *(const i32x4*)(Bs + rdB[ni][kk]);
#pragma unroll
            for (int mi = 0; mi < 2; ++mi)
#pragma unroll
                for (int ni = 0; ni < 2; ++ni)
                    acc[mi][ni] = __builtin_amdgcn_mfma_i32_32x32x32_i8(
                        af[mi], bf[ni], acc[mi][ni], 0, 0, 0);
        }
        __syncthreads();
    }

    // Epilogue. C/D layout (32x32, dtype-independent): col = lane&31,
    // row = (reg&3) + 8*(reg>>2) + 4*(lane>>5).
    const float asc = fmaxf(fabsf(ascale[0]), EPSQ);
#pragma unroll
    for (int ni = 0; ni < 2; ++ni) {
        const int n  = n_tile + wn + ni * 32 + (lane & 31);
        const float sc = asc * fmaxf(fabsf(wscale[n]), EPSQ);
        const float bb = bias[n];
#pragma unroll
        for (int mi = 0; mi < 2; ++mi) {
            const int rbase = m_tile + wm + mi * 32 + 4 * (lane >> 5);
#pragma unroll
            for (int r = 0; r < 16; ++r) {
                const int row = rbase + (r & 3) + 8 * (r >> 2);
                out[(size_t)row * OUT_F + n] = sc * (float)acc[mi][ni][r] + bb;
            }
        }
    }
}

// ---------------------------------------------------------------------------
extern "C" void kernel_launch(void* const* d_in, const int* in_sizes, int n_in,
                              void* d_out, int out_size, void* d_ws, size_t ws_size,
                              hipStream_t stream) {
    const float* x      = (const float*)d_in[0];
    const float* W      = (const float*)d_in[1];
    const float* lA     = (const float*)d_in[2];
    const float* lB     = (const float*)d_in[3];
    const float* wscale = (const float*)d_in[4];
    const float* ascale = (const float*)d_in[5];
    const float* bias   = (const float*)d_in[6];
    float* out = (float*)d_out;

    const int M = in_sizes[0] / IN_F;          // 8192
    int8_t* qx = (int8_t*)d_ws;                             // M*K bytes
    int8_t* qw = qx + (size_t)M * IN_F;                     // N*K bytes

    // 1) quantize x (4 elems/thread)
    qx_kernel<<<(in_sizes[0] / 4 + 255) / 256, 256, 0, stream>>>(x, ascale, qx);
    // 2) LoRA-merge + quantize weights (64x256 tiles)
    qw_kernel<<<dim3(IN_F / 256, OUT_F / 64), 256, 0, stream>>>(W, lA, lB, wscale, qw);
    // 3) int8 MFMA GEMM
    gemm_i8_kernel<<<dim3(OUT_F / BN, M / BM), 256, 0, stream>>>(
        qx, qw, wscale, ascale, bias, out);
}

// Round 2
// 430.022 us; speedup vs baseline: 1.0271x; 1.0271x over previous
//
#include <hip/hip_runtime.h>
#include <cstdint>
#include <cstddef>

#define IN_F 4096
#define OUT_F 4096
#define RANKK 16
#define EPSQ 1e-8f
#define LSCALE 0.01f

typedef __attribute__((ext_vector_type(4))) int i32x4;
typedef __attribute__((ext_vector_type(16))) int i32x16;

__device__ __forceinline__ float quantf(float v, float s) {
    float q = rintf(v / s);             // RNE, matches jnp.round
    return fminf(7.f, fmaxf(-8.f, q));
}

// Swizzle mask: bijective over both candidate LDS phase-groupings
// (8 rows x 1 chunk, and 4 rows x 2 chunks) -> conflict-free either way.
__device__ __forceinline__ int swzmask(int m) {
    return (((m >> 1) & 1) << 1) | ((m >> 2) & 1);
}

// ---------------------------------------------------------------------------
// Kernel 1: quantize activations x -> int8 in [-8,7].  4 elems/thread.
// ---------------------------------------------------------------------------
__global__ __launch_bounds__(256) void qx_kernel(const float* __restrict__ x,
                                                 const float* __restrict__ ascale,
                                                 int8_t* __restrict__ qx) {
    const float asc = fmaxf(fabsf(ascale[0]), EPSQ);
    const int i = blockIdx.x * 256 + threadIdx.x;
    float4 v = ((const float4*)x)[i];
    union { int8_t b[4]; int w; } u;
    u.b[0] = (int8_t)(int)quantf(v.x, asc);
    u.b[1] = (int8_t)(int)quantf(v.y, asc);
    u.b[2] = (int8_t)(int)quantf(v.z, asc);
    u.b[3] = (int8_t)(int)quantf(v.w, asc);
    ((int*)qx)[i] = u.w;
}

// ---------------------------------------------------------------------------
// Kernel 2: merged = W + 0.01 * (lora_B @ lora_A); quantize per output row.
// ---------------------------------------------------------------------------
__global__ __launch_bounds__(256) void qw_kernel(const float* __restrict__ W,
                                                 const float* __restrict__ lA,
                                                 const float* __restrict__ lB,
                                                 const float* __restrict__ wscale,
                                                 int8_t* __restrict__ qw) {
    __shared__ float Ablk[RANKK][256];   // 16 KB
    __shared__ float Bblk[64][RANKK];    // 4 KB
    const int tid = threadIdx.x;
    const int i0 = blockIdx.x * 256;
    const int o0 = blockIdx.y * 64;

#pragma unroll
    for (int r = 0; r < RANKK; ++r)
        Ablk[r][tid] = lA[r * IN_F + i0 + tid];
    for (int j = tid; j < 64 * RANKK; j += 256)
        Bblk[j >> 4][j & 15] = lB[(size_t)(o0 + (j >> 4)) * RANKK + (j & 15)];
    __syncthreads();

    const int i = i0 + tid;
#pragma unroll 4
    for (int o = 0; o < 64; ++o) {
        float s = 0.f;
#pragma unroll
        for (int r = 0; r < RANKK; ++r) s += Bblk[o][r] * Ablk[r][tid];
        float merged = W[(size_t)(o0 + o) * IN_F + i] + LSCALE * s;
        float wsc = fmaxf(fabsf(wscale[o0 + o]), EPSQ);
        qw[(size_t)(o0 + o) * IN_F + i] = (int8_t)(int)quantf(merged, wsc);
    }
}

// ---------------------------------------------------------------------------
// Kernel 3: int8 GEMM.  BM=128 x BN=256, BK=64, 4 waves each computing a
// 64x128 wave-tile as 2x4 of mfma_i32_32x32x32_i8 -> 6 ds_read_b128 per
// 8 MFMA (was 8:8).  XOR chunk swizzle with bit-reversed mask (conflict-free
// for both 8x1 and 4x2 LDS phase groupings).
// ---------------------------------------------------------------------------
constexpr int BM = 128, BN = 256, BK = 64, KD = 4096;

__global__ __launch_bounds__(256, 2) void gemm_i8_kernel(
        const int8_t* __restrict__ qx, const int8_t* __restrict__ qw,
        const float* __restrict__ wscale, const float* __restrict__ ascale,
        const float* __restrict__ bias, float* __restrict__ out) {
    __shared__ __attribute__((aligned(16))) int8_t As[BM * BK];  // 8 KB
    __shared__ __attribute__((aligned(16))) int8_t Bs[BN * BK];  // 16 KB

    const int tid  = threadIdx.x;
    const int lane = tid & 63;
    const int wave = tid >> 6;
    const int hi   = lane >> 5;
    const int m_tile = blockIdx.y * BM;
    const int n_tile = blockIdx.x * BN;
    const int wm = (wave >> 1) * 64;    // wave row offset (0 or 64)
    const int wn = (wave & 1) * 128;    // wave col offset (0 or 128)

    // ---- staging source offsets (per-lane): LDS chunk p holds global chunk
    // (m = p>>2, q = (p&3) ^ swzmask(m)).
    int srcA[2], srcB[4];
#pragma unroll
    for (int is = 0; is < 2; ++is) {
        int p = is * 256 + tid;
        int m = p >> 2;
        int q = (p & 3) ^ swzmask(m);
        srcA[is] = m * KD + q * 16;
    }
#pragma unroll
    for (int is = 0; is < 4; ++is) {
        int p = is * 256 + tid;
        int m = p >> 2;
        int q = (p & 3) ^ swzmask(m);
        srcB[is] = m * KD + q * 16;
    }
    const int8_t* Abase = qx + (size_t)m_tile * KD;
    const int8_t* Bbase = qw + (size_t)n_tile * KD;

    // ---- fragment read bases: row ra, needed chunk q = kk*2 + hi,
    // LDS slot = q ^ swzmask(ra).
    int baseA[2], maskA[2], baseB[4], maskB[4];
#pragma unroll
    for (int mi = 0; mi < 2; ++mi) {
        const int ra = wm + mi * 32 + (lane & 31);
        baseA[mi] = ra * 64;
        maskA[mi] = swzmask(ra);
    }
#pragma unroll
    for (int ni = 0; ni < 4; ++ni) {
        const int rb = wn + ni * 32 + (lane & 31);
        baseB[ni] = rb * 64;
        maskB[ni] = swzmask(rb);
    }

    i32x16 acc[2][4];
#pragma unroll
    for (int mi = 0; mi < 2; ++mi)
#pragma unroll
        for (int ni = 0; ni < 4; ++ni) acc[mi][ni] = (i32x16)(0);

    for (int k0 = 0; k0 < KD; k0 += BK) {
#pragma unroll
        for (int is = 0; is < 2; ++is)
            __builtin_amdgcn_global_load_lds(
                (const __attribute__((address_space(1))) void*)(Abase + k0 + srcA[is]),
                (__attribute__((address_space(3))) void*)(As + (is * 256 + wave * 64) * 16),
                16, 0, 0);
#pragma unroll
        for (int is = 0; is < 4; ++is)
            __builtin_amdgcn_global_load_lds(
                (const __attribute__((address_space(1))) void*)(Bbase + k0 + srcB[is]),
                (__attribute__((address_space(3))) void*)(Bs + (is * 256 + wave * 64) * 16),
                16, 0, 0);
        __syncthreads();
#pragma unroll
        for (int kk = 0; kk < 2; ++kk) {
            const int q = kk * 2 + hi;
            i32x4 af[2], bf[4];
#pragma unroll
            for (int mi = 0; mi < 2; ++mi)
                af[mi] = *(const i32x4*)(As + baseA[mi] + ((q ^ maskA[mi]) * 16));
#pragma unroll
            for (int ni = 0; ni < 4; ++ni)
                bf[ni] = *(const i32x4*)(Bs + baseB[ni] + ((q ^ maskB[ni]) * 16));
#pragma unroll
            for (int mi = 0; mi < 2; ++mi)
#pragma unroll
                for (int ni = 0; ni < 4; ++ni)
                    acc[mi][ni] = __builtin_amdgcn_mfma_i32_32x32x32_i8(
                        af[mi], bf[ni], acc[mi][ni], 0, 0, 0);
        }
        __syncthreads();
    }

    // ---- epilogue.  C/D layout: col = lane&31, row = (r&3)+8*(r>>2)+4*hi.
    const float asc = fmaxf(fabsf(ascale[0]), EPSQ);
#pragma unroll
    for (int ni = 0; ni < 4; ++ni) {
        const int n  = n_tile + wn + ni * 32 + (lane & 31);
        const float sc = asc * fmaxf(fabsf(wscale[n]), EPSQ);
        const float bb = bias[n];
#pragma unroll
        for (int mi = 0; mi < 2; ++mi) {
            const int rbase = m_tile + wm + mi * 32 + 4 * hi;
#pragma unroll
            for (int r = 0; r < 16; ++r) {
                const int row = rbase + (r & 3) + 8 * (r >> 2);
                out[(size_t)row * OUT_F + n] = sc * (float)acc[mi][ni][r] + bb;
            }
        }
    }
}

// ---------------------------------------------------------------------------
extern "C" void kernel_launch(void* const* d_in, const int* in_sizes, int n_in,
                              void* d_out, int out_size, void* d_ws, size_t ws_size,
                              hipStream_t stream) {
    const float* x      = (const float*)d_in[0];
    const float* W      = (const float*)d_in[1];
    const float* lA     = (const float*)d_in[2];
    const float* lB     = (const float*)d_in[3];
    const float* wscale = (const float*)d_in[4];
    const float* ascale = (const float*)d_in[5];
    const float* bias   = (const float*)d_in[6];
    float* out = (float*)d_out;

    const int M = in_sizes[0] / IN_F;          // 8192
    int8_t* qx = (int8_t*)d_ws;                             // M*K bytes
    int8_t* qw = qx + (size_t)M * IN_F;                     // N*K bytes

    qx_kernel<<<(in_sizes[0] / 4 + 255) / 256, 256, 0, stream>>>(x, ascale, qx);
    qw_kernel<<<dim3(IN_F / 256, OUT_F / 64), 256, 0, stream>>>(W, lA, lB, wscale, qw);
    gemm_i8_kernel<<<dim3(OUT_F / BN, M / BM), 256, 0, stream>>>(
        qx, qw, wscale, ascale, bias, out);
}

// Round 3
// 415.439 us; speedup vs baseline: 1.0631x; 1.0351x over previous
//
#include <hip/hip_runtime.h>
#include <cstdint>
#include <cstddef>

#define IN_F 4096
#define OUT_F 4096
#define RANKK 16
#define EPSQ 1e-8f
#define LSCALE 0.01f

typedef __attribute__((ext_vector_type(4))) int i32x4;
typedef __attribute__((ext_vector_type(16))) int i32x16;

__device__ __forceinline__ float quantf(float v, float s) {
    float q = rintf(v / s);             // RNE, matches jnp.round
    return fminf(7.f, fmaxf(-8.f, q));
}

// ---------------------------------------------------------------------------
// Kernel 1: quantize activations x -> int8 in [-8,7].  4 elems/thread.
// ---------------------------------------------------------------------------
__global__ __launch_bounds__(256) void qx_kernel(const float* __restrict__ x,
                                                 const float* __restrict__ ascale,
                                                 int8_t* __restrict__ qx) {
    const float asc = fmaxf(fabsf(ascale[0]), EPSQ);
    const int i = blockIdx.x * 256 + threadIdx.x;
    float4 v = ((const float4*)x)[i];
    union { int8_t b[4]; int w; } u;
    u.b[0] = (int8_t)(int)quantf(v.x, asc);
    u.b[1] = (int8_t)(int)quantf(v.y, asc);
    u.b[2] = (int8_t)(int)quantf(v.z, asc);
    u.b[3] = (int8_t)(int)quantf(v.w, asc);
    ((int*)qx)[i] = u.w;
}

// ---------------------------------------------------------------------------
// Kernel 2: merged = W + 0.01 * (lora_B @ lora_A); quantize per output row.
// ---------------------------------------------------------------------------
__global__ __launch_bounds__(256) void qw_kernel(const float* __restrict__ W,
                                                 const float* __restrict__ lA,
                                                 const float* __restrict__ lB,
                                                 const float* __restrict__ wscale,
                                                 int8_t* __restrict__ qw) {
    __shared__ float Ablk[RANKK][256];   // 16 KB
    __shared__ float Bblk[64][RANKK];    // 4 KB
    const int tid = threadIdx.x;
    const int i0 = blockIdx.x * 256;
    const int o0 = blockIdx.y * 64;

#pragma unroll
    for (int r = 0; r < RANKK; ++r)
        Ablk[r][tid] = lA[r * IN_F + i0 + tid];
    for (int j = tid; j < 64 * RANKK; j += 256)
        Bblk[j >> 4][j & 15] = lB[(size_t)(o0 + (j >> 4)) * RANKK + (j & 15)];
    __syncthreads();

    const int i = i0 + tid;
#pragma unroll 4
    for (int o = 0; o < 64; ++o) {
        float s = 0.f;
#pragma unroll
        for (int r = 0; r < RANKK; ++r) s += Bblk[o][r] * Ablk[r][tid];
        float merged = W[(size_t)(o0 + o) * IN_F + i] + LSCALE * s;
        float wsc = fmaxf(fabsf(wscale[o0 + o]), EPSQ);
        qw[(size_t)(o0 + o) * IN_F + i] = (int8_t)(int)quantf(merged, wsc);
    }
}

// ---------------------------------------------------------------------------
// Kernel 3: int8 GEMM.  BM=128 x BN=256, BK=128 (halve barrier-drain count
// vs BK=64; LDS 48 KB keeps 2 blocks/CU since we're VGPR-bound anyway).
// 4 waves x (2x4 of mfma_i32_32x32x32_i8).  Row = 128 B = 8 chunks of 16 B;
// chunk swizzle c = q ^ (row&7) (bijective per 8-row phase group; residual
// 2-way aliasing in the 4x2 grouping is free per m136).  The measured
// 4 conflict-cyc per ds_read_b128 is intrinsic (m134) — not swizzle-fixable.
// ---------------------------------------------------------------------------
constexpr int BM = 128, BN = 256, BK = 128, KD = 4096;

__global__ __launch_bounds__(256, 2) void gemm_i8_kernel(
        const int8_t* __restrict__ qx, const int8_t* __restrict__ qw,
        const float* __restrict__ wscale, const float* __restrict__ ascale,
        const float* __restrict__ bias, float* __restrict__ out) {
    __shared__ __attribute__((aligned(16))) int8_t As[BM * BK];  // 16 KB
    __shared__ __attribute__((aligned(16))) int8_t Bs[BN * BK];  // 32 KB

    const int tid  = threadIdx.x;
    const int lane = tid & 63;
    const int wave = tid >> 6;
    const int hi   = lane >> 5;
    const int m_tile = blockIdx.y * BM;
    const int n_tile = blockIdx.x * BN;
    const int wm = (wave >> 1) * 64;    // wave row offset (0 or 64)
    const int wn = (wave & 1) * 128;    // wave col offset (0 or 128)

    // ---- staging source offsets: LDS chunk p holds global chunk
    // (m = p>>3, q = (p&7) ^ (m&7)).  One instruction = 1 KB contiguous LDS.
    int srcA[4], srcB[8];
#pragma unroll
    for (int is = 0; is < 4; ++is) {
        int p = is * 256 + tid;
        int m = p >> 3;
        int q = (p & 7) ^ (m & 7);
        srcA[is] = m * KD + q * 16;
    }
#pragma unroll
    for (int is = 0; is < 8; ++is) {
        int p = is * 256 + tid;
        int m = p >> 3;
        int q = (p & 7) ^ (m & 7);
        srcB[is] = m * KD + q * 16;
    }
    const int8_t* Abase = qx + (size_t)m_tile * KD;
    const int8_t* Bbase = qw + (size_t)n_tile * KD;

    // ---- fragment read bases: row r, chunk q = kk*2 + hi, slot = q ^ (r&7).
    int baseA[2], maskA[2], baseB[4], maskB[4];
#pragma unroll
    for (int mi = 0; mi < 2; ++mi) {
        const int ra = wm + mi * 32 + (lane & 31);
        baseA[mi] = ra * BK;
        maskA[mi] = ra & 7;
    }
#pragma unroll
    for (int ni = 0; ni < 4; ++ni) {
        const int rb = wn + ni * 32 + (lane & 31);
        baseB[ni] = rb * BK;
        maskB[ni] = rb & 7;
    }

    i32x16 acc[2][4];
#pragma unroll
    for (int mi = 0; mi < 2; ++mi)
#pragma unroll
        for (int ni = 0; ni < 4; ++ni) acc[mi][ni] = (i32x16)(0);

    for (int k0 = 0; k0 < KD; k0 += BK) {
#pragma unroll
        for (int is = 0; is < 4; ++is)
            __builtin_amdgcn_global_load_lds(
                (const __attribute__((address_space(1))) void*)(Abase + k0 + srcA[is]),
                (__attribute__((address_space(3))) void*)(As + (is * 256 + wave * 64) * 16),
                16, 0, 0);
#pragma unroll
        for (int is = 0; is < 8; ++is)
            __builtin_amdgcn_global_load_lds(
                (const __attribute__((address_space(1))) void*)(Bbase + k0 + srcB[is]),
                (__attribute__((address_space(3))) void*)(Bs + (is * 256 + wave * 64) * 16),
                16, 0, 0);
        __syncthreads();
#pragma unroll
        for (int kk = 0; kk < 4; ++kk) {
            const int q = kk * 2 + hi;
            i32x4 af[2], bf[4];
#pragma unroll
            for (int mi = 0; mi < 2; ++mi)
                af[mi] = *(const i32x4*)(As + baseA[mi] + ((q ^ maskA[mi]) * 16));
#pragma unroll
            for (int ni = 0; ni < 4; ++ni)
                bf[ni] = *(const i32x4*)(Bs + baseB[ni] + ((q ^ maskB[ni]) * 16));
#pragma unroll
            for (int mi = 0; mi < 2; ++mi)
#pragma unroll
                for (int ni = 0; ni < 4; ++ni)
                    acc[mi][ni] = __builtin_amdgcn_mfma_i32_32x32x32_i8(
                        af[mi], bf[ni], acc[mi][ni], 0, 0, 0);
        }
        __syncthreads();
    }

    // ---- epilogue.  C/D layout: col = lane&31, row = (r&3)+8*(r>>2)+4*hi.
    const float asc = fmaxf(fabsf(ascale[0]), EPSQ);
#pragma unroll
    for (int ni = 0; ni < 4; ++ni) {
        const int n  = n_tile + wn + ni * 32 + (lane & 31);
        const float sc = asc * fmaxf(fabsf(wscale[n]), EPSQ);
        const float bb = bias[n];
#pragma unroll
        for (int mi = 0; mi < 2; ++mi) {
            const int rbase = m_tile + wm + mi * 32 + 4 * hi;
#pragma unroll
            for (int r = 0; r < 16; ++r) {
                const int row = rbase + (r & 3) + 8 * (r >> 2);
                out[(size_t)row * OUT_F + n] = sc * (float)acc[mi][ni][r] + bb;
            }
        }
    }
}

// ---------------------------------------------------------------------------
extern "C" void kernel_launch(void* const* d_in, const int* in_sizes, int n_in,
                              void* d_out, int out_size, void* d_ws, size_t ws_size,
                              hipStream_t stream) {
    const float* x      = (const float*)d_in[0];
    const float* W      = (const float*)d_in[1];
    const float* lA     = (const float*)d_in[2];
    const float* lB     = (const float*)d_in[3];
    const float* wscale = (const float*)d_in[4];
    const float* ascale = (const float*)d_in[5];
    const float* bias   = (const float*)d_in[6];
    float* out = (float*)d_out;

    const int M = in_sizes[0] / IN_F;          // 8192
    int8_t* qx = (int8_t*)d_ws;                             // M*K bytes
    int8_t* qw = qx + (size_t)M * IN_F;                     // N*K bytes

    qx_kernel<<<(in_sizes[0] / 4 + 255) / 256, 256, 0, stream>>>(x, ascale, qx);
    qw_kernel<<<dim3(IN_F / 256, OUT_F / 64), 256, 0, stream>>>(W, lA, lB, wscale, qw);
    gemm_i8_kernel<<<dim3(OUT_F / BN, M / BM), 256, 0, stream>>>(
        qx, qw, wscale, ascale, bias, out);
}